// Round 15
// baseline (887.911 us; speedup 1.0000x reference)
//
#include <hip/hip_runtime.h>

#define NU    100000
#define NI    100000
#define NNZE  3200000
#define D     128

#define SROWS 512                 // rows per segment
#define SEGS  196                 // segments per side = ceil(100000/512)
#define NSEG  392                 // both sides
#define CAPA  18432               // u64 append slots per segment (mean 16384, +16 sigma)
#define STG   24                  // LDS staging entries per bucket (75KB -> 2 blocks/CU)
#define CAPL  64                  // bin slots per row
#define OVFCAP 65536

typedef unsigned long long u64;

__device__ __forceinline__ unsigned bf16r(float x) {
    unsigned u = __float_as_uint(x);
    return (u + 0x7FFFu + ((u >> 16) & 1u)) >> 16;   // RNE
}
__device__ __forceinline__ void push_ovf(u64* __restrict__ ovf, int* __restrict__ ovfcnt,
                                         int row, int col, unsigned vbits, int side) {
    int p = atomicAdd(ovfcnt, 1);
    if (p < OVFCAP) {
        ovf[p] = (u64)(unsigned)row
               | ((u64)(unsigned)col << 17)
               | ((u64)(((vbits + 0x8000u) >> 16) & 0xFFFFu) << 34)
               | ((u64)(unsigned)side << 50);
    }
}

// ---------- phase A: LDS-staged segment partition + fused bf16 cvt ----------
// entry u64: [0:8]=row_local(512), [9:25]=col, [32:63]=f32 val bits
// Wave-parallel flushes (r15): lane0 allocates, 64 lanes store; 2 blocks/CU.
__global__ __launch_bounds__(512) void phaseA_kernel(
        const int* __restrict__ urows, const int* __restrict__ ucols,
        const float* __restrict__ uvals,
        const int* __restrict__ irows, const int* __restrict__ icols,
        const float* __restrict__ ivals,
        int* __restrict__ cur, u64* __restrict__ appends,
        u64* __restrict__ ovf, int* __restrict__ ovfcnt,
        const float* __restrict__ input, unsigned short* __restrict__ tabb) {
    __shared__ u64 stage[NSEG * STG];   // 75.3 KB
    __shared__ int scnt[NSEG];
    for (int b = threadIdx.x; b < NSEG; b += 512) scnt[b] = 0;
    __syncthreads();

    const int wv = threadIdx.x >> 6;   // wave 0..7
    const int ln = threadIdx.x & 63;

    const int nth  = gridDim.x * 512;
    const int gid0 = blockIdx.x * 512 + threadIdx.x;
    const int rounds = (NNZE + nth - 1) / nth;

    for (int rd = 0; rd < rounds; ++rd) {
        const int e = rd * nth + gid0;
        if (e < NNZE) {
            {
                const int r = urows[e], c = ucols[e];
                const unsigned vb = __float_as_uint(uvals[e]);
                const int b = r >> 9;
                const int p = atomicAdd(&scnt[b], 1);
                const u64 ent = ((u64)vb << 32) | ((u64)(unsigned)c << 9) | (unsigned)(r & 511);
                if (p < STG) stage[b * STG + p] = ent;
                else push_ovf(ovf, ovfcnt, r, c, vb, 0);
            }
            {
                const int r = irows[e], c = icols[e];
                const unsigned vb = __float_as_uint(ivals[e]);
                const int b = SEGS + (r >> 9);
                const int p = atomicAdd(&scnt[b], 1);
                const u64 ent = ((u64)vb << 32) | ((u64)(unsigned)c << 9) | (unsigned)(r & 511);
                if (p < STG) stage[b * STG + p] = ent;
                else push_ovf(ovf, ovfcnt, r, c, vb, 1);
            }
        }
        __syncthreads();
        // wave-parallel flush: wave wv owns buckets wv, wv+8, ...
        for (int b = wv; b < NSEG; b += 8) {
            int c = scnt[b]; if (c > STG) c = STG;
            const int nf = c & ~15;               // 0 or 16
            if (nf) {
                int base0 = 0;
                if (ln == 0) base0 = atomicAdd(&cur[b], nf);
                base0 = __shfl(base0, 0);
                if (ln < nf) {
                    const u64 ent = stage[b * STG + ln];
                    const int idx = base0 + ln;
                    if (idx < CAPA) {
                        appends[(size_t)b * CAPA + idx] = ent;
                    } else {
                        const int side = (b >= SEGS) ? 1 : 0;
                        push_ovf(ovf, ovfcnt,
                                 (((b - side * SEGS) << 9) | (int)(ent & 511u)),
                                 (int)((ent >> 9) & 0x1FFFFu), (unsigned)(ent >> 32), side);
                    }
                }
                const int rem = c - nf;           // <= 8
                u64 moved = 0;
                if (ln < rem) moved = stage[b * STG + nf + ln];   // reads [16,24)
                if (ln < rem) stage[b * STG + ln] = moved;        // writes [0,8)
                if (ln == 0) scnt[b] = rem;
            }
        }
        __syncthreads();
    }
    // drain remainders (wave-parallel, <16 each)
    for (int b = wv; b < NSEG; b += 8) {
        int c = scnt[b]; if (c > STG) c = STG;
        if (c) {
            int base0 = 0;
            if (ln == 0) base0 = atomicAdd(&cur[b], c);
            base0 = __shfl(base0, 0);
            if (ln < c) {
                const u64 ent = stage[b * STG + ln];
                const int idx = base0 + ln;
                if (idx < CAPA) {
                    appends[(size_t)b * CAPA + idx] = ent;
                } else {
                    const int side = (b >= SEGS) ? 1 : 0;
                    push_ovf(ovf, ovfcnt,
                             (((b - side * SEGS) << 9) | (int)(ent & 511u)),
                             (int)((ent >> 9) & 0x1FFFFu), (unsigned)(ent >> 32), side);
                }
            }
        }
    }
    // fused cvt: f32 table -> bf16 table (streaming, overlaps stragglers)
    const int total = (NU + NI) * D / 8;
    for (int i = blockIdx.x * 512 + threadIdx.x; i < total; i += nth) {
        const float4 a = reinterpret_cast<const float4*>(input)[2 * i];
        const float4 b = reinterpret_cast<const float4*>(input)[2 * i + 1];
        uint4 w;
        w.x = bf16r(a.x) | (bf16r(a.y) << 16);
        w.y = bf16r(a.z) | (bf16r(a.w) << 16);
        w.z = bf16r(b.x) | (bf16r(b.y) << 16);
        w.w = bf16r(b.z) | (bf16r(b.w) << 16);
        reinterpret_cast<uint4*>(tabb)[i] = w;
    }
}

// ---------- phase B: LDS-bin one segment, zero-pad to x16, write in place ----
__global__ __launch_bounds__(256) void phaseB_kernel(
        const int* __restrict__ cur, u64* __restrict__ appends,
        int* __restrict__ cntG, u64* __restrict__ ovf, int* __restrict__ ovfcnt) {
    __shared__ int cnt[SROWS];                  // 2 KB
    __shared__ unsigned bins[SROWS * CAPL];     // 128 KB
    const int seg = blockIdx.x;
    const int side = (seg >= SEGS) ? 1 : 0;
    const int seg_side = seg - side * SEGS;

    for (int i = threadIdx.x; i < SROWS; i += 256) cnt[i] = 0;
    __syncthreads();

    int na = cur[seg]; if (na > CAPA) na = CAPA;
    u64* abase = appends + (size_t)seg * CAPA;
    for (int t = threadIdx.x; t < na; t += 256) {
        const u64 ent = abase[t];
        const int rl  = (int)(ent & 511u);
        const int col = (int)((ent >> 9) & 0x1FFFFu);
        const unsigned vb = (unsigned)(ent >> 32);
        const int p = atomicAdd(&cnt[rl], 1);
        if (p < CAPL) bins[(rl << 6) + p] = ((unsigned)col << 15) | (((vb + 0x8000u) >> 16) & 0x7FFFu);
        else push_ovf(ovf, ovfcnt, (seg_side << 9) + rl, col, vb, side);
    }
    __syncthreads();

    // zero-pad each row's bins up to a multiple of 16 (entry 0 = col 0, val 0)
    for (int r = threadIdx.x; r < SROWS; r += 256) {
        int c = cnt[r]; if (c > CAPL) c = CAPL;
        const int p = (c + 15) & ~15;            // 0,16,32,48,64
        for (int k = c; k < p; ++k) bins[(r << 6) + k] = 0u;
        cnt[r] = p;
    }
    __syncthreads();

    // dense full-line writeback over the append region (reads all done)
    uint4* gb = reinterpret_cast<uint4*>(abase);          // 128 KB <= CAPA*8
    const uint4* lb = reinterpret_cast<const uint4*>(bins);
    for (int i = threadIdx.x; i < SROWS * CAPL / 4; i += 256) gb[i] = lb[i];

    int* cbase = cntG + side * (SEGS * SROWS) + (seg_side << 9);
    for (int i = threadIdx.x; i < SROWS; i += 256) cbase[i] = cnt[i];
}

// ---------- pull over bf16 table: branch-free, 4 gathers in flight ----------
__global__ void pull_bf16_kernel(const unsigned short* __restrict__ tabb,
                                 const int* __restrict__ cntG,
                                 const u64* __restrict__ appends,
                                 float* __restrict__ out) {
    const int wid = (int)(((size_t)blockIdx.x * blockDim.x + threadIdx.x) >> 6);
    if (wid >= NU + NI) return;
    const int lane = threadIdx.x & 63;
    const int q    = lane >> 4;
    const int s16  = lane & 15;
    const int side = (wid >= NU) ? 1 : 0;
    const int row  = wid - side * NU;
    const unsigned short* src = tabb + (size_t)side * NU * D;
    float* dst = out + (size_t)side * NU * D;

    const int n = cntG[side * (SEGS * SROWS) + row];     // multiple of 16, <= 64
    const int gseg = side * SEGS + (row >> 9);
    const unsigned* brow =
        reinterpret_cast<const unsigned*>(appends + (size_t)gseg * CAPA) + ((row & 511) << 6);

    float acc[8];
#pragma unroll
    for (int k = 0; k < 8; ++k) acc[k] = 0.f;

    const unsigned ent = brow[lane];                     // 64 slots always valid
    const int   c = (int)(ent >> 15);
    const float v = __uint_as_float((ent & 0x7FFFu) << 16);

    for (int j = 0; j < n; j += 16) {                    // 16 edges per step
        int cc[4]; float vv[4]; uint4 x[4];
#pragma unroll
        for (int t = 0; t < 4; ++t) {
            const int jj = j + 4 * t + q;
            cc[t] = __shfl(c, jj); vv[t] = __shfl(v, jj);
        }
#pragma unroll
        for (int t = 0; t < 4; ++t) {
            x[t] = reinterpret_cast<const uint4*>(src + (size_t)cc[t] * D)[s16];
        }
#pragma unroll
        for (int t = 0; t < 4; ++t) {
#pragma unroll
            for (int w = 0; w < 4; ++w) {
                const unsigned u = (&x[t].x)[w];
                acc[2*w]   += __uint_as_float(u << 16)         * vv[t];
                acc[2*w+1] += __uint_as_float(u & 0xFFFF0000u) * vv[t];
            }
        }
    }
#pragma unroll
    for (int k = 0; k < 8; ++k) {
        acc[k] += __shfl_xor(acc[k], 16);
        acc[k] += __shfl_xor(acc[k], 32);
    }
    if (q == 0) {
        float4 o0, o1;
        o0.x = acc[0]; o0.y = acc[1]; o0.z = acc[2]; o0.w = acc[3];
        o1.x = acc[4]; o1.y = acc[5]; o1.z = acc[6]; o1.w = acc[7];
        float4* op = reinterpret_cast<float4*>(dst + (size_t)row * D + 8 * s16);
        op[0] = o0; op[1] = o1;
    }
}

// ---------- overflow tail (f32 atomics, after pull) ----------
__global__ void tail_ovf_kernel(const float* __restrict__ input,
                                const u64* __restrict__ ovf,
                                const int* __restrict__ ovfcnt,
                                float* __restrict__ out) {
    int cntv = *ovfcnt;
    if (cntv > OVFCAP) cntv = OVFCAP;
    const long long total = (long long)cntv * 64;
    long long gid = (long long)blockIdx.x * blockDim.x + threadIdx.x;
    const long long stride = (long long)gridDim.x * blockDim.x;
    for (; gid < total; gid += stride) {
        const int e    = (int)(gid >> 6);
        const int lane = (int)(gid & 63);
        const u64 en = ovf[e];
        const int row  = (int)(en & 0x1FFFFu);
        const int col  = (int)((en >> 17) & 0x1FFFFu);
        const float v  = __uint_as_float((unsigned)((en >> 34) & 0xFFFFu) << 16);
        const int side = (int)((en >> 50) & 1u);
        const float* s = input + (size_t)side * NU * D;
        float*       d = out   + (size_t)side * NU * D;
        atomicAdd(&d[(size_t)row * D + 2 * lane],     s[(size_t)col * D + 2 * lane]     * v);
        atomicAdd(&d[(size_t)row * D + 2 * lane + 1], s[(size_t)col * D + 2 * lane + 1] * v);
    }
}

// ================= tier 2: CSR build (known-correct fallback) =========
__global__ void hist_kernel(const int* __restrict__ urows,
                            const int* __restrict__ irows,
                            int* __restrict__ cnt_u, int* __restrict__ cnt_i) {
    int gid = blockIdx.x * blockDim.x + threadIdx.x;
    int stride = gridDim.x * blockDim.x;
    for (int e = gid; e < NNZE; e += stride) {
        atomicAdd(&cnt_u[urows[e]], 1);
        atomicAdd(&cnt_i[irows[e]], 1);
    }
}

__global__ void scan_kernel(int* __restrict__ cnt_u, int* __restrict__ off_u,
                            int* __restrict__ cnt_i, int* __restrict__ off_i) {
    int* cnt = (blockIdx.x == 0) ? cnt_u : cnt_i;
    int* off = (blockIdx.x == 0) ? off_u : off_i;
    const int n = (blockIdx.x == 0) ? NU : NI;
    __shared__ int lds[1024];
    int carry = 0;
    for (int base = 0; base < n; base += 1024) {
        const int i = base + (int)threadIdx.x;
        const int v = (i < n) ? cnt[i] : 0;
        lds[threadIdx.x] = v;
        __syncthreads();
        for (int ofs = 1; ofs < 1024; ofs <<= 1) {
            int t = (threadIdx.x >= (unsigned)ofs) ? lds[threadIdx.x - ofs] : 0;
            __syncthreads();
            lds[threadIdx.x] += t;
            __syncthreads();
        }
        const int incl = lds[threadIdx.x];
        const int excl = incl - v;
        if (i < n) {
            off[i] = carry + excl;
            cnt[i] = carry + excl;
        }
        carry += lds[1023];
        __syncthreads();
    }
    if (threadIdx.x == 0) off[n] = carry;
}

__global__ void scatter_kernel(const int* __restrict__ urows,
                               const int* __restrict__ irows,
                               int* __restrict__ cur_u, int* __restrict__ cur_i,
                               int* __restrict__ perm_u, int* __restrict__ perm_i) {
    int gid = blockIdx.x * blockDim.x + threadIdx.x;
    int stride = gridDim.x * blockDim.x;
    for (int e = gid; e < NNZE; e += stride) {
        int p = atomicAdd(&cur_u[urows[e]], 1);
        perm_u[p] = e;
        p = atomicAdd(&cur_i[irows[e]], 1);
        perm_i[p] = e;
    }
}

__global__ void pull_csr_kernel(const float* __restrict__ input,
                                const int* __restrict__ ucols, const float* __restrict__ uvals,
                                const int* __restrict__ icols, const float* __restrict__ ivals,
                                const int* __restrict__ off_u, const int* __restrict__ perm_u,
                                const int* __restrict__ off_i, const int* __restrict__ perm_i,
                                float* __restrict__ out) {
    const int wid = (int)(((size_t)blockIdx.x * blockDim.x + threadIdx.x) >> 6);
    if (wid >= NU + NI) return;
    const int lane = threadIdx.x & 63;
    const int* off; const int* perm; const int* cols; const float* vals;
    const float* src; float* dst; int row;
    if (wid < NU) {
        off = off_u; perm = perm_u; cols = ucols; vals = uvals;
        src = input; dst = out; row = wid;
    } else {
        off = off_i; perm = perm_i; cols = icols; vals = ivals;
        src = input + (size_t)NU * D; dst = out + (size_t)NU * D; row = wid - NU;
    }
    const int s = off[row];
    const int n = off[row + 1] - s;
    float accx = 0.f, accy = 0.f;
    for (int base = 0; base < n; base += 64) {
        int m = n - base; if (m > 64) m = 64;
        int c = 0; float v = 0.f;
        if (lane < m) {
            const int nz = perm[s + base + lane];
            c = cols[nz];
            v = vals[nz];
        }
        for (int j = 0; j < m; ++j) {
            const int   cc = __shfl(c, j);
            const float vv = __shfl(v, j);
            const float2 x = reinterpret_cast<const float2*>(src + (size_t)cc * D)[lane];
            accx += x.x * vv; accy += x.y * vv;
        }
    }
    float2 o; o.x = accx; o.y = accy;
    reinterpret_cast<float2*>(dst + (size_t)row * D)[lane] = o;
}

// ================= tier 3: atomic scatter fallback =========================
__global__ void spmm_scatter_kernel(const float* __restrict__ input,
                                    const int* __restrict__ urows,
                                    const int* __restrict__ ucols,
                                    const float* __restrict__ uvals,
                                    const int* __restrict__ irows,
                                    const int* __restrict__ icols,
                                    const float* __restrict__ ivals,
                                    float* __restrict__ out) {
    const long long total = 2LL * NNZE * 32;
    long long gid = (long long)blockIdx.x * blockDim.x + threadIdx.x;
    const long long stride = (long long)gridDim.x * blockDim.x;
    for (; gid < total; gid += stride) {
        const int e = (int)(gid >> 5);
        const int qq = (int)(gid & 31);
        int row, col; float val; const float* src; float* dst;
        if (e < NNZE) {
            row = urows[e]; col = ucols[e]; val = uvals[e];
            src = input; dst = out;
        } else {
            const int e2 = e - NNZE;
            row = irows[e2]; col = icols[e2]; val = ivals[e2];
            src = input + (long long)NU * D; dst = out + (long long)NU * D;
        }
        const float4 v = reinterpret_cast<const float4*>(src + (long long)col * D)[qq];
        float* o = dst + (long long)row * D + (qq << 2);
        atomicAdd(o + 0, v.x * val);
        atomicAdd(o + 1, v.y * val);
        atomicAdd(o + 2, v.z * val);
        atomicAdd(o + 3, v.w * val);
    }
}

extern "C" void kernel_launch(void* const* d_in, const int* in_sizes, int n_in,
                              void* d_out, int out_size, void* d_ws, size_t ws_size,
                              hipStream_t stream) {
    const float* input = (const float*)d_in[0];
    const int*   urows = (const int*)d_in[1];
    const int*   ucols = (const int*)d_in[2];
    const float* uvals = (const float*)d_in[3];
    const int*   irows = (const int*)d_in[4];
    const int*   icols = (const int*)d_in[5];
    const float* ivals = (const float*)d_in[6];
    float*       out   = (float*)d_out;

    // tier-1 layout: [appends NSEG*CAPA u64][ovf][cur NSEG + ovfcnt][cnt 2*SEGS*SROWS][tabb]
    const size_t appends_b = (size_t)NSEG * CAPA * 8;          // 57,802,752
    const size_t ovf_b     = (size_t)OVFCAP * 8;               // 524,288
    const size_t cur_b     = ((size_t)(NSEG + 1) * 4 + 15) & ~(size_t)15;
    const size_t cnt_b     = (size_t)2 * SEGS * SROWS * 4;     // 802,816
    const size_t tabb_b    = (size_t)(NU + NI) * D * 2;        // 51,200,000
    const size_t need_t1   = appends_b + ovf_b + cur_b + cnt_b + tabb_b;  // ~110.3 MB

    const size_t need_csr = ((size_t)NU + NI + (NU + 1) + (NI + 1) + 2 * (size_t)NNZE) * 4;

    if (ws_size >= need_t1) {
        char* base = (char*)d_ws;
        u64* appends = (u64*)base;
        u64* ovf     = (u64*)(base + appends_b);
        int* cur     = (int*)(base + appends_b + ovf_b);
        int* ovfcnt  = cur + NSEG;
        int* cntG    = (int*)(base + appends_b + ovf_b + cur_b);
        unsigned short* tabb = (unsigned short*)(base + appends_b + ovf_b + cur_b + cnt_b);

        hipMemsetAsync(cur, 0, (size_t)(NSEG + 1) * sizeof(int), stream);
        phaseA_kernel<<<512, 512, 0, stream>>>(
            urows, ucols, uvals, irows, icols, ivals, cur, appends, ovf, ovfcnt,
            input, tabb);
        phaseB_kernel<<<NSEG, 256, 0, stream>>>(cur, appends, cntG, ovf, ovfcnt);
        pull_bf16_kernel<<<(NU + NI + 3) / 4, 256, 0, stream>>>(tabb, cntG, appends, out);
        tail_ovf_kernel<<<64, 256, 0, stream>>>(input, ovf, ovfcnt, out);
    } else if (ws_size >= need_csr) {
        int* cur_u  = (int*)d_ws;
        int* cur_i  = cur_u + NU;
        int* off_u  = cur_i + NI;
        int* off_i  = off_u + (NU + 1);
        int* perm_u = off_i + (NI + 1);
        int* perm_i = perm_u + NNZE;

        hipMemsetAsync(cur_u, 0, (size_t)(NU + NI) * sizeof(int), stream);
        hist_kernel<<<2048, 256, 0, stream>>>(urows, irows, cur_u, cur_i);
        scan_kernel<<<2, 1024, 0, stream>>>(cur_u, off_u, cur_i, off_i);
        scatter_kernel<<<2048, 256, 0, stream>>>(urows, irows, cur_u, cur_i, perm_u, perm_i);
        pull_csr_kernel<<<(NU + NI + 3) / 4, 256, 0, stream>>>(
            input, ucols, uvals, icols, ivals, off_u, perm_u, off_i, perm_i, out);
    } else {
        hipMemsetAsync(out, 0, (size_t)out_size * sizeof(float), stream);
        spmm_scatter_kernel<<<8192, 256, 0, stream>>>(
            input, urows, ucols, uvals, irows, icols, ivals, out);
    }
}

// Round 16
// 485.547 us; speedup vs baseline: 1.8287x; 1.8287x over previous
//
#include <hip/hip_runtime.h>

#define NU    100000
#define NI    100000
#define NNZE  3200000
#define D     128

#define SROWS 512                 // rows per segment
#define SEGS  196                 // segments per side = ceil(100000/512)
#define NSEG  392                 // both sides
#define CAPA  18432               // u64 append slots per segment (mean 16384, +16 sigma)
#define STG   32                  // LDS staging entries per bucket (r13-proven)
#define CAPL  64                  // bin slots per row
#define OVFCAP 65536

typedef unsigned long long u64;

__device__ __forceinline__ unsigned bf16r(float x) {
    unsigned u = __float_as_uint(x);
    return (u + 0x7FFFu + ((u >> 16) & 1u)) >> 16;   // RNE
}
__device__ __forceinline__ void push_ovf(u64* __restrict__ ovf, int* __restrict__ ovfcnt,
                                         int row, int col, unsigned vbits, int side) {
    int p = atomicAdd(ovfcnt, 1);
    if (p < OVFCAP) {
        ovf[p] = (u64)(unsigned)row
               | ((u64)(unsigned)col << 17)
               | ((u64)(((vbits + 0x8000u) >> 16) & 0xFFFFu) << 34)
               | ((u64)(unsigned)side << 50);
    }
}

// ---------- tier 1a: f32 table -> bf16 table ----------
__global__ void cvt_kernel(const float* __restrict__ in, unsigned short* __restrict__ outb) {
    const int total = (NU + NI) * D / 8;
    int gid = blockIdx.x * blockDim.x + threadIdx.x;
    const int stride = gridDim.x * blockDim.x;
    for (int i = gid; i < total; i += stride) {
        const float4 a = reinterpret_cast<const float4*>(in)[2 * i];
        const float4 b = reinterpret_cast<const float4*>(in)[2 * i + 1];
        uint4 w;
        w.x = bf16r(a.x) | (bf16r(a.y) << 16);
        w.y = bf16r(a.z) | (bf16r(a.w) << 16);
        w.z = bf16r(b.x) | (bf16r(b.y) << 16);
        w.w = bf16r(b.z) | (bf16r(b.w) << 16);
        reinterpret_cast<uint4*>(outb)[i] = w;
    }
}

// ---------- phase A: LDS-staged segment partition (r13-proven form) ----------
// entry u64: [0:8]=row_local(512), [9:25]=col, [32:63]=f32 val bits
__global__ __launch_bounds__(512) void phaseA_kernel(
        const int* __restrict__ urows, const int* __restrict__ ucols,
        const float* __restrict__ uvals,
        const int* __restrict__ irows, const int* __restrict__ icols,
        const float* __restrict__ ivals,
        int* __restrict__ cur, u64* __restrict__ appends,
        u64* __restrict__ ovf, int* __restrict__ ovfcnt) {
    __shared__ u64 stage[NSEG * STG];   // ~98 KB
    __shared__ int scnt[NSEG];
    for (int b = threadIdx.x; b < NSEG; b += 512) scnt[b] = 0;
    __syncthreads();

    const int nth  = gridDim.x * 512;
    const int gid0 = blockIdx.x * 512 + threadIdx.x;
    const int rounds = (NNZE + nth - 1) / nth;

    for (int rd = 0; rd < rounds; ++rd) {
        const int e = rd * nth + gid0;
        if (e < NNZE) {
            {
                const int r = urows[e], c = ucols[e];
                const unsigned vb = __float_as_uint(uvals[e]);
                const int b = r >> 9;
                const int p = atomicAdd(&scnt[b], 1);
                const u64 ent = ((u64)vb << 32) | ((u64)(unsigned)c << 9) | (unsigned)(r & 511);
                if (p < STG) stage[b * STG + p] = ent;
                else push_ovf(ovf, ovfcnt, r, c, vb, 0);
            }
            {
                const int r = irows[e], c = icols[e];
                const unsigned vb = __float_as_uint(ivals[e]);
                const int b = SEGS + (r >> 9);
                const int p = atomicAdd(&scnt[b], 1);
                const u64 ent = ((u64)vb << 32) | ((u64)(unsigned)c << 9) | (unsigned)(r & 511);
                if (p < STG) stage[b * STG + p] = ent;
                else push_ovf(ovf, ovfcnt, r, c, vb, 1);
            }
        }
        __syncthreads();
        if (threadIdx.x < NSEG) {
            const int b = threadIdx.x;
            int c = scnt[b]; if (c > STG) c = STG;
            const int nf = c & ~15;               // flush 16 or 32
            if (nf) {
                const int base = atomicAdd(&cur[b], nf);
                for (int k = 0; k < nf; ++k) {
                    const int idx = base + k;
                    const u64 ent = stage[b * STG + k];
                    if (idx < CAPA) {
                        appends[(size_t)b * CAPA + idx] = ent;
                    } else {
                        const int side = (b >= SEGS) ? 1 : 0;
                        push_ovf(ovf, ovfcnt,
                                 (((b - side * SEGS) << 9) | (int)(ent & 511u)),
                                 (int)((ent >> 9) & 0x1FFFFu), (unsigned)(ent >> 32), side);
                    }
                }
                for (int k = 0; k < c - nf; ++k) stage[b * STG + k] = stage[b * STG + nf + k];
                c -= nf;
            }
            scnt[b] = c;
        }
        __syncthreads();
    }
    // drain remainders (<16 each)
    if (threadIdx.x < NSEG) {
        const int b = threadIdx.x;
        int c = scnt[b]; if (c > STG) c = STG;
        if (c) {
            const int base = atomicAdd(&cur[b], c);
            for (int k = 0; k < c; ++k) {
                const int idx = base + k;
                const u64 ent = stage[b * STG + k];
                if (idx < CAPA) {
                    appends[(size_t)b * CAPA + idx] = ent;
                } else {
                    const int side = (b >= SEGS) ? 1 : 0;
                    push_ovf(ovf, ovfcnt,
                             (((b - side * SEGS) << 9) | (int)(ent & 511u)),
                             (int)((ent >> 9) & 0x1FFFFu), (unsigned)(ent >> 32), side);
                }
            }
        }
    }
}

// ---------- phase B: LDS-bin one segment (512 thr), zero-pad, write in place --
__global__ __launch_bounds__(512) void phaseB_kernel(
        const int* __restrict__ cur, u64* __restrict__ appends,
        int* __restrict__ cntG, u64* __restrict__ ovf, int* __restrict__ ovfcnt) {
    __shared__ int cnt[SROWS];                  // 2 KB
    __shared__ unsigned bins[SROWS * CAPL];     // 128 KB
    const int seg = blockIdx.x;
    const int side = (seg >= SEGS) ? 1 : 0;
    const int seg_side = seg - side * SEGS;

    for (int i = threadIdx.x; i < SROWS; i += 512) cnt[i] = 0;
    __syncthreads();

    int na = cur[seg]; if (na > CAPA) na = CAPA;
    u64* abase = appends + (size_t)seg * CAPA;
    for (int t = threadIdx.x; t < na; t += 512) {
        const u64 ent = abase[t];
        const int rl  = (int)(ent & 511u);
        const int col = (int)((ent >> 9) & 0x1FFFFu);
        const unsigned vb = (unsigned)(ent >> 32);
        const int p = atomicAdd(&cnt[rl], 1);
        if (p < CAPL) bins[(rl << 6) + p] = ((unsigned)col << 15) | (((vb + 0x8000u) >> 16) & 0x7FFFu);
        else push_ovf(ovf, ovfcnt, (seg_side << 9) + rl, col, vb, side);
    }
    __syncthreads();

    // zero-pad each row's bins up to a multiple of 16 (entry 0 = col 0, val 0)
    for (int r = threadIdx.x; r < SROWS; r += 512) {
        int c = cnt[r]; if (c > CAPL) c = CAPL;
        const int p = (c + 15) & ~15;            // 0,16,32,48,64
        for (int k = c; k < p; ++k) bins[(r << 6) + k] = 0u;
        cnt[r] = p;
    }
    __syncthreads();

    // dense full-line writeback over the append region (reads all done)
    uint4* gb = reinterpret_cast<uint4*>(abase);          // 128 KB <= CAPA*8
    const uint4* lb = reinterpret_cast<const uint4*>(bins);
    for (int i = threadIdx.x; i < SROWS * CAPL / 4; i += 512) gb[i] = lb[i];

    int* cbase = cntG + side * (SEGS * SROWS) + (seg_side << 9);
    for (int i = threadIdx.x; i < SROWS; i += 512) cbase[i] = cnt[i];
}

// ---------- pull over bf16 table: branch-free, 4 gathers in flight ----------
__global__ void pull_bf16_kernel(const unsigned short* __restrict__ tabb,
                                 const int* __restrict__ cntG,
                                 const u64* __restrict__ appends,
                                 float* __restrict__ out) {
    const int wid = (int)(((size_t)blockIdx.x * blockDim.x + threadIdx.x) >> 6);
    if (wid >= NU + NI) return;
    const int lane = threadIdx.x & 63;
    const int q    = lane >> 4;
    const int s16  = lane & 15;
    const int side = (wid >= NU) ? 1 : 0;
    const int row  = wid - side * NU;
    const unsigned short* src = tabb + (size_t)side * NU * D;
    float* dst = out + (size_t)side * NU * D;

    const int n = cntG[side * (SEGS * SROWS) + row];     // multiple of 16, <= 64
    const int gseg = side * SEGS + (row >> 9);
    const unsigned* brow =
        reinterpret_cast<const unsigned*>(appends + (size_t)gseg * CAPA) + ((row & 511) << 6);

    float acc[8];
#pragma unroll
    for (int k = 0; k < 8; ++k) acc[k] = 0.f;

    const unsigned ent = brow[lane];                     // 64 slots always valid
    const int   c = (int)(ent >> 15);
    const float v = __uint_as_float((ent & 0x7FFFu) << 16);

    for (int j = 0; j < n; j += 16) {                    // 16 edges per step
        int cc[4]; float vv[4]; uint4 x[4];
#pragma unroll
        for (int t = 0; t < 4; ++t) {
            const int jj = j + 4 * t + q;
            cc[t] = __shfl(c, jj); vv[t] = __shfl(v, jj);
        }
#pragma unroll
        for (int t = 0; t < 4; ++t) {
            x[t] = reinterpret_cast<const uint4*>(src + (size_t)cc[t] * D)[s16];
        }
#pragma unroll
        for (int t = 0; t < 4; ++t) {
#pragma unroll
            for (int w = 0; w < 4; ++w) {
                const unsigned u = (&x[t].x)[w];
                acc[2*w]   += __uint_as_float(u << 16)         * vv[t];
                acc[2*w+1] += __uint_as_float(u & 0xFFFF0000u) * vv[t];
            }
        }
    }
#pragma unroll
    for (int k = 0; k < 8; ++k) {
        acc[k] += __shfl_xor(acc[k], 16);
        acc[k] += __shfl_xor(acc[k], 32);
    }
    if (q == 0) {
        float4 o0, o1;
        o0.x = acc[0]; o0.y = acc[1]; o0.z = acc[2]; o0.w = acc[3];
        o1.x = acc[4]; o1.y = acc[5]; o1.z = acc[6]; o1.w = acc[7];
        float4* op = reinterpret_cast<float4*>(dst + (size_t)row * D + 8 * s16);
        op[0] = o0; op[1] = o1;
    }
}

// ---------- overflow tail (f32 atomics, after pull) ----------
__global__ void tail_ovf_kernel(const float* __restrict__ input,
                                const u64* __restrict__ ovf,
                                const int* __restrict__ ovfcnt,
                                float* __restrict__ out) {
    int cntv = *ovfcnt;
    if (cntv > OVFCAP) cntv = OVFCAP;
    const long long total = (long long)cntv * 64;
    long long gid = (long long)blockIdx.x * blockDim.x + threadIdx.x;
    const long long stride = (long long)gridDim.x * blockDim.x;
    for (; gid < total; gid += stride) {
        const int e    = (int)(gid >> 6);
        const int lane = (int)(gid & 63);
        const u64 en = ovf[e];
        const int row  = (int)(en & 0x1FFFFu);
        const int col  = (int)((en >> 17) & 0x1FFFFu);
        const float v  = __uint_as_float((unsigned)((en >> 34) & 0xFFFFu) << 16);
        const int side = (int)((en >> 50) & 1u);
        const float* s = input + (size_t)side * NU * D;
        float*       d = out   + (size_t)side * NU * D;
        atomicAdd(&d[(size_t)row * D + 2 * lane],     s[(size_t)col * D + 2 * lane]     * v);
        atomicAdd(&d[(size_t)row * D + 2 * lane + 1], s[(size_t)col * D + 2 * lane + 1] * v);
    }
}

// ================= tier 2: CSR build (known-correct fallback) =========
__global__ void hist_kernel(const int* __restrict__ urows,
                            const int* __restrict__ irows,
                            int* __restrict__ cnt_u, int* __restrict__ cnt_i) {
    int gid = blockIdx.x * blockDim.x + threadIdx.x;
    int stride = gridDim.x * blockDim.x;
    for (int e = gid; e < NNZE; e += stride) {
        atomicAdd(&cnt_u[urows[e]], 1);
        atomicAdd(&cnt_i[irows[e]], 1);
    }
}

__global__ void scan_kernel(int* __restrict__ cnt_u, int* __restrict__ off_u,
                            int* __restrict__ cnt_i, int* __restrict__ off_i) {
    int* cnt = (blockIdx.x == 0) ? cnt_u : cnt_i;
    int* off = (blockIdx.x == 0) ? off_u : off_i;
    const int n = (blockIdx.x == 0) ? NU : NI;
    __shared__ int lds[1024];
    int carry = 0;
    for (int base = 0; base < n; base += 1024) {
        const int i = base + (int)threadIdx.x;
        const int v = (i < n) ? cnt[i] : 0;
        lds[threadIdx.x] = v;
        __syncthreads();
        for (int ofs = 1; ofs < 1024; ofs <<= 1) {
            int t = (threadIdx.x >= (unsigned)ofs) ? lds[threadIdx.x - ofs] : 0;
            __syncthreads();
            lds[threadIdx.x] += t;
            __syncthreads();
        }
        const int incl = lds[threadIdx.x];
        const int excl = incl - v;
        if (i < n) {
            off[i] = carry + excl;
            cnt[i] = carry + excl;
        }
        carry += lds[1023];
        __syncthreads();
    }
    if (threadIdx.x == 0) off[n] = carry;
}

__global__ void scatter_kernel(const int* __restrict__ urows,
                               const int* __restrict__ irows,
                               int* __restrict__ cur_u, int* __restrict__ cur_i,
                               int* __restrict__ perm_u, int* __restrict__ perm_i) {
    int gid = blockIdx.x * blockDim.x + threadIdx.x;
    int stride = gridDim.x * blockDim.x;
    for (int e = gid; e < NNZE; e += stride) {
        int p = atomicAdd(&cur_u[urows[e]], 1);
        perm_u[p] = e;
        p = atomicAdd(&cur_i[irows[e]], 1);
        perm_i[p] = e;
    }
}

__global__ void pull_csr_kernel(const float* __restrict__ input,
                                const int* __restrict__ ucols, const float* __restrict__ uvals,
                                const int* __restrict__ icols, const float* __restrict__ ivals,
                                const int* __restrict__ off_u, const int* __restrict__ perm_u,
                                const int* __restrict__ off_i, const int* __restrict__ perm_i,
                                float* __restrict__ out) {
    const int wid = (int)(((size_t)blockIdx.x * blockDim.x + threadIdx.x) >> 6);
    if (wid >= NU + NI) return;
    const int lane = threadIdx.x & 63;
    const int* off; const int* perm; const int* cols; const float* vals;
    const float* src; float* dst; int row;
    if (wid < NU) {
        off = off_u; perm = perm_u; cols = ucols; vals = uvals;
        src = input; dst = out; row = wid;
    } else {
        off = off_i; perm = perm_i; cols = icols; vals = ivals;
        src = input + (size_t)NU * D; dst = out + (size_t)NU * D; row = wid - NU;
    }
    const int s = off[row];
    const int n = off[row + 1] - s;
    float accx = 0.f, accy = 0.f;
    for (int base = 0; base < n; base += 64) {
        int m = n - base; if (m > 64) m = 64;
        int c = 0; float v = 0.f;
        if (lane < m) {
            const int nz = perm[s + base + lane];
            c = cols[nz];
            v = vals[nz];
        }
        for (int j = 0; j < m; ++j) {
            const int   cc = __shfl(c, j);
            const float vv = __shfl(v, j);
            const float2 x = reinterpret_cast<const float2*>(src + (size_t)cc * D)[lane];
            accx += x.x * vv; accy += x.y * vv;
        }
    }
    float2 o; o.x = accx; o.y = accy;
    reinterpret_cast<float2*>(dst + (size_t)row * D)[lane] = o;
}

// ================= tier 3: atomic scatter fallback =========================
__global__ void spmm_scatter_kernel(const float* __restrict__ input,
                                    const int* __restrict__ urows,
                                    const int* __restrict__ ucols,
                                    const float* __restrict__ uvals,
                                    const int* __restrict__ irows,
                                    const int* __restrict__ icols,
                                    const float* __restrict__ ivals,
                                    float* __restrict__ out) {
    const long long total = 2LL * NNZE * 32;
    long long gid = (long long)blockIdx.x * blockDim.x + threadIdx.x;
    const long long stride = (long long)gridDim.x * blockDim.x;
    for (; gid < total; gid += stride) {
        const int e = (int)(gid >> 5);
        const int qq = (int)(gid & 31);
        int row, col; float val; const float* src; float* dst;
        if (e < NNZE) {
            row = urows[e]; col = ucols[e]; val = uvals[e];
            src = input; dst = out;
        } else {
            const int e2 = e - NNZE;
            row = irows[e2]; col = icols[e2]; val = ivals[e2];
            src = input + (long long)NU * D; dst = out + (long long)NU * D;
        }
        const float4 v = reinterpret_cast<const float4*>(src + (long long)col * D)[qq];
        float* o = dst + (long long)row * D + (qq << 2);
        atomicAdd(o + 0, v.x * val);
        atomicAdd(o + 1, v.y * val);
        atomicAdd(o + 2, v.z * val);
        atomicAdd(o + 3, v.w * val);
    }
}

extern "C" void kernel_launch(void* const* d_in, const int* in_sizes, int n_in,
                              void* d_out, int out_size, void* d_ws, size_t ws_size,
                              hipStream_t stream) {
    const float* input = (const float*)d_in[0];
    const int*   urows = (const int*)d_in[1];
    const int*   ucols = (const int*)d_in[2];
    const float* uvals = (const float*)d_in[3];
    const int*   irows = (const int*)d_in[4];
    const int*   icols = (const int*)d_in[5];
    const float* ivals = (const float*)d_in[6];
    float*       out   = (float*)d_out;

    // tier-1 layout: [appends NSEG*CAPA u64][ovf][cur NSEG + ovfcnt][cnt 2*SEGS*SROWS][tabb]
    const size_t appends_b = (size_t)NSEG * CAPA * 8;          // 57,802,752
    const size_t ovf_b     = (size_t)OVFCAP * 8;               // 524,288
    const size_t cur_b     = ((size_t)(NSEG + 1) * 4 + 15) & ~(size_t)15;
    const size_t cnt_b     = (size_t)2 * SEGS * SROWS * 4;     // 802,816
    const size_t tabb_b    = (size_t)(NU + NI) * D * 2;        // 51,200,000
    const size_t need_t1   = appends_b + ovf_b + cur_b + cnt_b + tabb_b;  // ~110.3 MB

    const size_t need_csr = ((size_t)NU + NI + (NU + 1) + (NI + 1) + 2 * (size_t)NNZE) * 4;

    if (ws_size >= need_t1) {
        char* base = (char*)d_ws;
        u64* appends = (u64*)base;
        u64* ovf     = (u64*)(base + appends_b);
        int* cur     = (int*)(base + appends_b + ovf_b);
        int* ovfcnt  = cur + NSEG;
        int* cntG    = (int*)(base + appends_b + ovf_b + cur_b);
        unsigned short* tabb = (unsigned short*)(base + appends_b + ovf_b + cur_b + cnt_b);

        hipMemsetAsync(cur, 0, (size_t)(NSEG + 1) * sizeof(int), stream);
        phaseA_kernel<<<256, 512, 0, stream>>>(
            urows, ucols, uvals, irows, icols, ivals, cur, appends, ovf, ovfcnt);
        cvt_kernel<<<4096, 256, 0, stream>>>(input, tabb);
        phaseB_kernel<<<NSEG, 512, 0, stream>>>(cur, appends, cntG, ovf, ovfcnt);
        pull_bf16_kernel<<<(NU + NI + 3) / 4, 256, 0, stream>>>(tabb, cntG, appends, out);
        tail_ovf_kernel<<<64, 256, 0, stream>>>(input, ovf, ovfcnt, out);
    } else if (ws_size >= need_csr) {
        int* cur_u  = (int*)d_ws;
        int* cur_i  = cur_u + NU;
        int* off_u  = cur_i + NI;
        int* off_i  = off_u + (NU + 1);
        int* perm_u = off_i + (NI + 1);
        int* perm_i = perm_u + NNZE;

        hipMemsetAsync(cur_u, 0, (size_t)(NU + NI) * sizeof(int), stream);
        hist_kernel<<<2048, 256, 0, stream>>>(urows, irows, cur_u, cur_i);
        scan_kernel<<<2, 1024, 0, stream>>>(cur_u, off_u, cur_i, off_i);
        scatter_kernel<<<2048, 256, 0, stream>>>(urows, irows, cur_u, cur_i, perm_u, perm_i);
        pull_csr_kernel<<<(NU + NI + 3) / 4, 256, 0, stream>>>(
            input, ucols, uvals, icols, ivals, off_u, perm_u, off_i, perm_i, out);
    } else {
        hipMemsetAsync(out, 0, (size_t)out_size * sizeof(float), stream);
        spmm_scatter_kernel<<<8192, 256, 0, stream>>>(
            input, urows, ucols, uvals, irows, icols, ivals, out);
    }
}